// Round 6
// baseline (174.237 us; speedup 1.0000x reference)
//
#include <hip/hip_runtime.h>
#include <hip/hip_bf16.h>
#include <math.h>

#define B_  4
#define C_  128
#define W_  4096
#define CH_ 64

#define QBLKS  (B_ * (W_ / 32))  // 512 32-query blocks

typedef __bf16 bf16;
typedef __attribute__((ext_vector_type(8))) __bf16 bf16x8;
typedef __attribute__((ext_vector_type(4))) __bf16 bf16x4;
typedef __attribute__((ext_vector_type(4))) float f32x4;
typedef __attribute__((ext_vector_type(4))) short short4v;

__device__ __forceinline__ f32x4 mfma32bf(bf16x8 a, bf16x8 b, f32x4 c) {
    return __builtin_amdgcn_mfma_f32_16x16x32_bf16(a, b, c, 0, 0, 0);
}
__device__ __forceinline__ f32x4 mfma16bf(bf16x4 a, short4v b, f32x4 c) {
    return __builtin_amdgcn_mfma_f32_16x16x16bf16_1k(__builtin_bit_cast(short4v, a), b, c, 0, 0, 0);
}

// ---------------------------------------------------------------------------
// Fragment-major scratch layouts (per batch, per 16-key block "jblk"):
//   Kfrag: [b][jblk][ kh0 | kh1 | kl0 | kl1 ]  each chunk = 64 lanes x 8 bf16
//   Vfrag: [b][jblk][ tt=0..7 ]               each chunk = 64 lanes x 4 bf16
// Q: [b][w][64] bf16 (hi and lo).
// ---------------------------------------------------------------------------

__global__ __launch_bounds__(256) void qproj_kernel(
    const float* __restrict__ x,
    const float* __restrict__ Wq, const float* __restrict__ bq,
    bf16* __restrict__ Qh, bf16* __restrict__ Ql)
{
    __shared__ float xt[C_][36];
    __shared__ float WL[CH_][C_ + 1];

    const int t  = threadIdx.x;
    const int b  = blockIdx.x >> 7;
    const int w0 = (blockIdx.x & 127) << 5;

    const size_t xbase = (size_t)b * C_ * W_ + w0;
    #pragma unroll
    for (int k = 0; k < 16; ++k) {
        int idx = t + k * 256;
        int c = idx >> 5, w = idx & 31;
        xt[c][w] = x[xbase + (size_t)c * W_ + w];
    }
    #pragma unroll
    for (int k = 0; k < 32; ++k) {
        int idx = t + k * 256;
        int o = idx >> 7, c = idx & 127;
        WL[o][c] = Wq[idx];
    }
    __syncthreads();

    const int o  = t & 63;
    const int wg = t >> 6;

    float acc[8];
    const float bv = bq[o];
    #pragma unroll
    for (int i = 0; i < 8; ++i) acc[i] = bv;

    #pragma unroll 4
    for (int c = 0; c < C_; ++c) {
        const float wv = WL[o][c];
        float xv[8];
        *(float4*)&xv[0] = *(const float4*)&xt[c][wg * 8 + 0];
        *(float4*)&xv[4] = *(const float4*)&xt[c][wg * 8 + 4];
        #pragma unroll
        for (int i = 0; i < 8; ++i) acc[i] = fmaf(wv, xv[i], acc[i]);
    }

    const size_t qbase = ((size_t)b * W_ + w0 + wg * 8) * CH_ + o;
    #pragma unroll
    for (int i = 0; i < 8; ++i) {
        float q  = acc[i];
        bf16 qh = (bf16)q;
        bf16 ql = (bf16)(q - (float)qh);
        Qh[qbase + (size_t)i * CH_] = qh;
        Ql[qbase + (size_t)i * CH_] = ql;
    }
}

__global__ __launch_bounds__(256) void kproj_kernel(
    const float* __restrict__ x,
    const float* __restrict__ Wk, const float* __restrict__ bk,
    bf16* __restrict__ Kfrag, bf16* __restrict__ Vfrag)
{
    __shared__ float xt[C_][36];
    __shared__ float WL[CH_][C_ + 1];

    const int t  = threadIdx.x;
    const int b  = blockIdx.x >> 7;
    const int w0 = (blockIdx.x & 127) << 5;

    const size_t xbase = (size_t)b * C_ * W_ + w0;
    #pragma unroll
    for (int k = 0; k < 16; ++k) {
        int idx = t + k * 256;
        int c = idx >> 5, w = idx & 31;
        xt[c][w] = x[xbase + (size_t)c * W_ + w];
    }
    #pragma unroll
    for (int k = 0; k < 32; ++k) {
        int idx = t + k * 256;
        int o = idx >> 7, c = idx & 127;
        WL[o][c] = Wk[idx];
    }
    __syncthreads();

    const int o  = t & 63;
    const int wg = t >> 6;

    float acc[8];
    const float bv = bk[o];
    #pragma unroll
    for (int i = 0; i < 8; ++i) acc[i] = bv;

    #pragma unroll 4
    for (int c = 0; c < C_; ++c) {
        const float wv = WL[o][c];
        float xv[8];
        *(float4*)&xv[0] = *(const float4*)&xt[c][wg * 8 + 0];
        *(float4*)&xv[4] = *(const float4*)&xt[c][wg * 8 + 4];
        #pragma unroll
        for (int i = 0; i < 8; ++i) acc[i] = fmaf(wv, xv[i], acc[i]);
    }

    const int jblk  = (w0 >> 4) + (wg >> 1);
    const int ibase = (wg & 1) * 8;
    const size_t kconst = (size_t)b * 524288 + (size_t)jblk * 2048
                        + (size_t)(o >> 5) * 512 + (size_t)((o >> 3) & 3) * 128
                        + (o & 7);
    #pragma unroll
    for (int i = 0; i < 8; ++i) {
        float kv = acc[i];
        bf16 kh = (bf16)kv;
        bf16 kl = (bf16)(kv - (float)kh);
        Kfrag[kconst + (size_t)(ibase + i) * 8]        = kh;
        Kfrag[kconst + (size_t)(ibase + i) * 8 + 1024] = kl;
    }

    const int li = o & 15, gi = o >> 4;
    const int jb = wg >> 1;
    bf16* vfb = Vfrag + (size_t)b * 524288 + (size_t)((w0 >> 4) + jb) * 2048;
    #pragma unroll
    for (int tti = 0; tti < 4; ++tti) {
        const int tt = (wg & 1) * 4 + tti;
        const float4 xv4 = *(const float4*)&xt[tt * 16 + li][jb * 16 + 4 * gi];
        bf16x4 v4;
        v4[0] = (bf16)xv4.x; v4[1] = (bf16)xv4.y;
        v4[2] = (bf16)xv4.z; v4[3] = (bf16)xv4.w;
        *(bf16x4*)(vfb + tt * 256 + o * 4) = v4;
    }
}

// ---------------------------------------------------------------------------
// Shared macros for attention kernels
// ---------------------------------------------------------------------------
#define LOADK(S, JB) { \
    const bf16* kp_ = KB + (size_t)(JB) * 2048; \
    kh0##S = *(const bf16x8*)(kp_); \
    kh1##S = *(const bf16x8*)(kp_ + 512); \
    kl0##S = *(const bf16x8*)(kp_ + 1024); \
    kl1##S = *(const bf16x8*)(kp_ + 1536); }

#define LOADV(S, JB) { \
    const bf16* vp_ = VB + (size_t)(JB) * 2048; \
    _Pragma("unroll") \
    for (int tt = 0; tt < 8; ++tt) \
        v##S[tt] = *(const bf16x4*)(vp_ + tt * 256); }

#define QKT(S, E, QH0, QH1, QL0, QL1) { \
    f32x4 ea = {0.f, 0.f, 0.f, 0.f}; \
    f32x4 eb = {0.f, 0.f, 0.f, 0.f}; \
    __builtin_amdgcn_s_setprio(1); \
    ea = mfma32bf(kh0##S, QH0, ea); \
    ea = mfma32bf(kl0##S, QH0, ea); \
    ea = mfma32bf(kh0##S, QL0, ea); \
    eb = mfma32bf(kh1##S, QH1, eb); \
    eb = mfma32bf(kl1##S, QH1, eb); \
    eb = mfma32bf(kh1##S, QL1, eb); \
    __builtin_amdgcn_s_setprio(0); \
    E[0] = ea[0] + eb[0]; E[1] = ea[1] + eb[1]; \
    E[2] = ea[2] + eb[2]; E[3] = ea[3] + eb[3]; }

#define SOFTMAX(E, M, L, OACC, PS) { \
    const float mt = fmaxf(fmaxf(E[0], E[1]), fmaxf(E[2], E[3])); \
    if (__builtin_expect(__any(mt > M + 8.0f), 0)) { \
        float mr = mt; \
        mr = fmaxf(mr, __shfl_xor(mr, 16)); \
        mr = fmaxf(mr, __shfl_xor(mr, 32)); \
        const float mn = fmaxf(M, mr); \
        const float sc = __expf(M - mn); \
        L *= sc; \
        _Pragma("unroll") \
        for (int t8 = 0; t8 < 8; ++t8) { \
            OACC[t8][0] *= sc; OACC[t8][1] *= sc; \
            OACC[t8][2] *= sc; OACC[t8][3] *= sc; } \
        M = mn; \
    } \
    const float p0 = __expf(E[0] - M); \
    const float p1 = __expf(E[1] - M); \
    const float p2 = __expf(E[2] - M); \
    const float p3 = __expf(E[3] - M); \
    L += (p0 + p1) + (p2 + p3); \
    bf16x4 pb; pb[0] = (bf16)p0; pb[1] = (bf16)p1; pb[2] = (bf16)p2; pb[3] = (bf16)p3; \
    PS = __builtin_bit_cast(short4v, pb); }

#define STEP2(S) { \
    f32x4 e0, e1; \
    QKT(S, e0, qh0_0, qh1_0, ql0_0, ql1_0) \
    QKT(S, e1, qh0_1, qh1_1, ql0_1, ql1_1) \
    short4v ps0, ps1; \
    SOFTMAX(e0, m0, l0, oacc0, ps0) \
    SOFTMAX(e1, m1, l1, oacc1, ps1) \
    __builtin_amdgcn_s_setprio(1); \
    _Pragma("unroll") \
    for (int t8 = 0; t8 < 8; ++t8) { \
        oacc0[t8] = mfma16bf(v##S[t8], ps0, oacc0[t8]); \
        oacc1[t8] = mfma16bf(v##S[t8], ps1, oacc1[t8]); } \
    __builtin_amdgcn_s_setprio(0); }

// ---------------------------------------------------------------------------
// Key-split flash attention partial: 32 queries/wave, (W/16)/NS jblks/block.
// ---------------------------------------------------------------------------
template<int NS>
__global__ __launch_bounds__(64) void attn_partial_kernel(
    const bf16* __restrict__ Qh, const bf16* __restrict__ Ql,
    const bf16* __restrict__ Kfrag, const bf16* __restrict__ Vfrag,
    bf16* __restrict__ Opart, float2* __restrict__ ml)
{
    constexpr int SJ = 256 / NS;              // jblks per split
    const int lane = threadIdx.x;
    const int li = lane & 15;
    const int gi = lane >> 4;

    // bijective XCD swizzle; split index slowest -> each XCD's K/V working
    // set is ~1MB (L2-resident).
    const int nwg = QBLKS * NS;
    const int bid = blockIdx.x;
    const int swz = (bid & 7) * (nwg / 8) + (bid >> 3);
    const int s   = swz >> 9;                 // swz / QBLKS
    const int qi  = swz & (QBLKS - 1);
    const int b   = qi >> 7;
    const int i0  = (qi & 127) << 5;

    const size_t qoff = ((size_t)b * W_ + i0 + li) * CH_ + 8 * gi;
    const bf16x8 qh0_0 = *(const bf16x8*)(Qh + qoff);
    const bf16x8 qh1_0 = *(const bf16x8*)(Qh + qoff + 32);
    const bf16x8 ql0_0 = *(const bf16x8*)(Ql + qoff);
    const bf16x8 ql1_0 = *(const bf16x8*)(Ql + qoff + 32);
    const bf16x8 qh0_1 = *(const bf16x8*)(Qh + qoff + 16 * CH_);
    const bf16x8 qh1_1 = *(const bf16x8*)(Qh + qoff + 16 * CH_ + 32);
    const bf16x8 ql0_1 = *(const bf16x8*)(Ql + qoff + 16 * CH_);
    const bf16x8 ql1_1 = *(const bf16x8*)(Ql + qoff + 16 * CH_ + 32);

    const bf16* KB = Kfrag + (size_t)b * 524288 + (size_t)lane * 8
                   + (size_t)s * SJ * 2048;
    const bf16* VB = Vfrag + (size_t)b * 524288 + (size_t)lane * 4
                   + (size_t)s * SJ * 2048;

    f32x4 oacc0[8], oacc1[8];
    #pragma unroll
    for (int t8 = 0; t8 < 8; ++t8) {
        oacc0[t8] = (f32x4){0.f, 0.f, 0.f, 0.f};
        oacc1[t8] = (f32x4){0.f, 0.f, 0.f, 0.f};
    }
    float m0 = -INFINITY, l0 = 0.f;
    float m1 = -INFINITY, l1 = 0.f;

    bf16x8 kh0A, kh1A, kl0A, kl1A, kh0B, kh1B, kl0B, kl1B;
    bf16x4 vA[8], vB[8];

    LOADK(A, 0) LOADV(A, 0)
    #pragma unroll 1
    for (int js = 0; js < SJ - 2; js += 2) {
        LOADK(B, js + 1) LOADV(B, js + 1)
        STEP2(A)
        LOADK(A, js + 2) LOADV(A, js + 2)
        STEP2(B)
    }
    LOADK(B, SJ - 1) LOADV(B, SJ - 1)
    STEP2(A)
    STEP2(B)

    l0 += __shfl_xor(l0, 16); l0 += __shfl_xor(l0, 32);
    l1 += __shfl_xor(l1, 16); l1 += __shfl_xor(l1, 32);

    const size_t pblk = (size_t)qi * NS + s;
    bf16* ob = Opart + pblk * 2 * 8 * 64 * 4;
    #pragma unroll
    for (int t8 = 0; t8 < 8; ++t8) {
        bf16x4 o0, o1;
        o0[0] = (bf16)oacc0[t8][0]; o0[1] = (bf16)oacc0[t8][1];
        o0[2] = (bf16)oacc0[t8][2]; o0[3] = (bf16)oacc0[t8][3];
        o1[0] = (bf16)oacc1[t8][0]; o1[1] = (bf16)oacc1[t8][1];
        o1[2] = (bf16)oacc1[t8][2]; o1[3] = (bf16)oacc1[t8][3];
        *(bf16x4*)(ob + ((size_t)t8 * 64 + lane) * 4)       = o0;
        *(bf16x4*)(ob + ((size_t)(8 + t8) * 64 + lane) * 4) = o1;
    }
    if (gi == 0) {
        ml[(pblk * 2 + 0) * 16 + li] = make_float2(m0, l0);
        ml[(pblk * 2 + 1) * 16 + li] = make_float2(m1, l1);
    }
}

// ---------------------------------------------------------------------------
// Merge: out[b][c][i] = sum_s e^{m_s-M} Opart_s / sum_s e^{m_s-M} l_s
// ---------------------------------------------------------------------------
template<int NS>
__global__ __launch_bounds__(256) void merge_kernel(
    const bf16* __restrict__ Opart, const float2* __restrict__ ml,
    float* __restrict__ out)
{
    const int t = threadIdx.x;
    const int lane = t & 63, grp = t >> 6;
    const int li = lane & 15, gi = lane >> 4;
    const int qi = blockIdx.x;
    const int b  = qi >> 7;
    const int i0 = (qi & 127) << 5;

    #pragma unroll
    for (int tile = 0; tile < 2; ++tile) {
        float ms[NS], ls[NS];
        float M = -INFINITY;
        #pragma unroll
        for (int s = 0; s < NS; ++s) {
            const float2 v = ml[(((size_t)qi * NS + s) * 2 + tile) * 16 + li];
            ms[s] = v.x; ls[s] = v.y;
            M = fmaxf(M, v.x);
        }
        float w[NS], den = 0.f;
        #pragma unroll
        for (int s = 0; s < NS; ++s) {
            w[s] = __expf(ms[s] - M);
            den += w[s] * ls[s];
        }
        const float inv = 1.0f / den;

        #pragma unroll
        for (int t8g = 0; t8g < 2; ++t8g) {
            const int t8 = grp * 2 + t8g;
            float acc[4] = {0.f, 0.f, 0.f, 0.f};
            #pragma unroll
            for (int s = 0; s < NS; ++s) {
                const bf16x4 o4 = *(const bf16x4*)(Opart
                    + ((((size_t)qi * NS + s) * 2 + tile) * 8 + t8) * 256
                    + (size_t)lane * 4);
                acc[0] = fmaf(w[s], (float)o4[0], acc[0]);
                acc[1] = fmaf(w[s], (float)o4[1], acc[1]);
                acc[2] = fmaf(w[s], (float)o4[2], acc[2]);
                acc[3] = fmaf(w[s], (float)o4[3], acc[3]);
            }
            const int c0 = t8 * 16 + gi * 4;
            const int i  = i0 + tile * 16 + li;
            float* ob = out + ((size_t)b * C_ + c0) * W_ + i;
            ob[0 * (size_t)W_] = acc[0] * inv;
            ob[1 * (size_t)W_] = acc[1] * inv;
            ob[2 * (size_t)W_] = acc[2] * inv;
            ob[3 * (size_t)W_] = acc[3] * inv;
        }
    }
}

// ---------------------------------------------------------------------------
// Fallback: 16 queries/wave, all keys, direct output (tier C).
// ---------------------------------------------------------------------------
#define STEP1(S) { \
    f32x4 e; \
    QKT(S, e, qh0, qh1, ql0, ql1) \
    short4v ps; \
    SOFTMAX(e, m, l, oacc, ps) \
    __builtin_amdgcn_s_setprio(1); \
    _Pragma("unroll") \
    for (int t8 = 0; t8 < 8; ++t8) \
        oacc[t8] = mfma16bf(v##S[t8], ps, oacc[t8]); \
    __builtin_amdgcn_s_setprio(0); }

__global__ __launch_bounds__(64) void attn_kernel(
    const bf16* __restrict__ Qh, const bf16* __restrict__ Ql,
    const bf16* __restrict__ Kfrag, const bf16* __restrict__ Vfrag,
    float* __restrict__ out)
{
    const int lane = threadIdx.x;
    const int li = lane & 15;
    const int gi = lane >> 4;

    const int nwg = B_ * (W_ / 16);
    const int bid = blockIdx.x;
    const int swz = (bid & 7) * (nwg / 8) + (bid >> 3);
    const int b   = swz >> 8;
    const int i0  = (swz & 255) << 4;

    const size_t qoff = ((size_t)b * W_ + i0 + li) * CH_ + 8 * gi;
    const bf16x8 qh0 = *(const bf16x8*)(Qh + qoff);
    const bf16x8 qh1 = *(const bf16x8*)(Qh + qoff + 32);
    const bf16x8 ql0 = *(const bf16x8*)(Ql + qoff);
    const bf16x8 ql1 = *(const bf16x8*)(Ql + qoff + 32);

    const bf16* KB = Kfrag + (size_t)b * 524288 + (size_t)lane * 8;
    const bf16* VB = Vfrag + (size_t)b * 524288 + (size_t)lane * 4;

    f32x4 oacc[8];
    #pragma unroll
    for (int t8 = 0; t8 < 8; ++t8) oacc[t8] = (f32x4){0.f, 0.f, 0.f, 0.f};
    float m = -INFINITY;
    float l = 0.f;

    bf16x8 kh0A, kh1A, kl0A, kl1A, kh0B, kh1B, kl0B, kl1B;
    bf16x4 vA[8], vB[8];

    LOADK(A, 0) LOADV(A, 0)
    #pragma unroll 1
    for (int js = 0; js < 254; js += 2) {
        LOADK(B, js + 1) LOADV(B, js + 1)
        STEP1(A)
        LOADK(A, js + 2) LOADV(A, js + 2)
        STEP1(B)
    }
    LOADK(B, 255) LOADV(B, 255)
    STEP1(A)
    STEP1(B)

    l += __shfl_xor(l, 16);
    l += __shfl_xor(l, 32);
    const float inv = 1.0f / l;

    float* ob = out + (size_t)b * C_ * W_ + i0 + li;
    #pragma unroll
    for (int t8 = 0; t8 < 8; ++t8) {
        const int c0 = t8 * 16 + gi * 4;
        ob[(size_t)(c0 + 0) * W_] = oacc[t8][0] * inv;
        ob[(size_t)(c0 + 1) * W_] = oacc[t8][1] * inv;
        ob[(size_t)(c0 + 2) * W_] = oacc[t8][2] * inv;
        ob[(size_t)(c0 + 3) * W_] = oacc[t8][3] * inv;
    }
}

extern "C" void kernel_launch(void* const* d_in, const int* in_sizes, int n_in,
                              void* d_out, int out_size, void* d_ws, size_t ws_size,
                              hipStream_t stream)
{
    (void)in_sizes; (void)n_in; (void)out_size;

    const float* x  = (const float*)d_in[0];
    const float* Wq = (const float*)d_in[1];
    const float* bq = (const float*)d_in[2];
    const float* Wk = (const float*)d_in[3];
    const float* bk = (const float*)d_in[4];
    float* out = (float*)d_out;

    char* ws = (char*)d_ws;
    const size_t MB = 1024 * 1024;
    bf16* Qh    = (bf16*)(ws + 0 * MB);
    bf16* Ql    = (bf16*)(ws + 2 * MB);
    bf16* Kfrag = (bf16*)(ws + 4 * MB);
    bf16* Vfrag = (bf16*)(ws + 8 * MB);
    bf16* Opart = (bf16*)(ws + 12 * MB);

    // tier A (NS=8): Opart 32MB @12MB, ml 1MB @44MB  -> need 45MB
    // tier B (NS=4): Opart 16MB @12MB, ml .5MB @28MB -> need 28.5MB (proven)
    const size_t needA = 45 * MB;
    const size_t needB = 28 * MB + (size_t)QBLKS * 4 * 2 * 16 * sizeof(float2);

    kproj_kernel<<<dim3(B_ * (W_ / 32)), dim3(256), 0, stream>>>(
        x, Wk, bk, Kfrag, Vfrag);
    qproj_kernel<<<dim3(B_ * (W_ / 32)), dim3(256), 0, stream>>>(
        x, Wq, bq, Qh, Ql);

    if (ws_size >= needA) {
        float2* ml = (float2*)(ws + 44 * MB);
        attn_partial_kernel<8><<<dim3(QBLKS * 8), dim3(64), 0, stream>>>(
            Qh, Ql, Kfrag, Vfrag, Opart, ml);
        merge_kernel<8><<<dim3(QBLKS), dim3(256), 0, stream>>>(Opart, ml, out);
    } else if (ws_size >= needB) {
        float2* ml = (float2*)(ws + 28 * MB);
        attn_partial_kernel<4><<<dim3(QBLKS * 4), dim3(64), 0, stream>>>(
            Qh, Ql, Kfrag, Vfrag, Opart, ml);
        merge_kernel<4><<<dim3(QBLKS), dim3(256), 0, stream>>>(Opart, ml, out);
    } else {
        attn_kernel<<<dim3(B_ * (W_ / 16)), dim3(64), 0, stream>>>(
            Qh, Ql, Kfrag, Vfrag, out);
    }
}

// Round 7
// 133.866 us; speedup vs baseline: 1.3016x; 1.3016x over previous
//
#include <hip/hip_runtime.h>
#include <hip/hip_bf16.h>
#include <math.h>

#define B_  4
#define C_  128
#define W_  4096
#define CH_ 64
#define LOG2E 1.44269504088896f

#define QBLKS  (B_ * (W_ / 32))  // 512 32-query blocks

typedef __bf16 bf16;
typedef __attribute__((ext_vector_type(8))) __bf16 bf16x8;
typedef __attribute__((ext_vector_type(4))) __bf16 bf16x4;
typedef __attribute__((ext_vector_type(4))) float f32x4;
typedef __attribute__((ext_vector_type(4))) short short4v;

__device__ __forceinline__ f32x4 mfma32bf(bf16x8 a, bf16x8 b, f32x4 c) {
    return __builtin_amdgcn_mfma_f32_16x16x32_bf16(a, b, c, 0, 0, 0);
}
__device__ __forceinline__ f32x4 mfma16bf(bf16x4 a, short4v b, f32x4 c) {
    return __builtin_amdgcn_mfma_f32_16x16x16bf16_1k(__builtin_bit_cast(short4v, a), b, c, 0, 0, 0);
}
// v_exp_f32 computes 2^x natively — one instruction, no log2e multiply.
__device__ __forceinline__ float exp2a(float x) {
    float r; asm("v_exp_f32 %0, %1" : "=v"(r) : "v"(x)); return r;
}

// ---------------------------------------------------------------------------
// Scratch layouts:
//   Qb   : [b][w][64] bf16, PRE-SCALED by log2(e)  (2 MB)
//   Kfrag: [b][jblk][ kh0 | kh1 ] chunks of 64 lanes x 8 bf16   (2 MB)
//          kh0: lane l -> K[j=jblk*16+(l&15)][ch=8*(l>>4)+0..7]; kh1: ch+=32
//   Vfrag: [b][jblk][ tt=0..7 ]   chunks of 64 lanes x 4 bf16   (4 MB)
//          lane l -> x_bf16[c=tt*16+(l&15)][w=jblk*16+4*(l>>4)+0..3]
// ---------------------------------------------------------------------------

__global__ __launch_bounds__(256) void qproj_kernel(
    const float* __restrict__ x,
    const float* __restrict__ Wq, const float* __restrict__ bq,
    bf16* __restrict__ Qb)
{
    __shared__ float xt[C_][36];
    __shared__ float WL[CH_][C_ + 1];

    const int t  = threadIdx.x;
    const int b  = blockIdx.x >> 7;
    const int w0 = (blockIdx.x & 127) << 5;

    const size_t xbase = (size_t)b * C_ * W_ + w0;
    #pragma unroll
    for (int k = 0; k < 16; ++k) {
        int idx = t + k * 256;
        int c = idx >> 5, w = idx & 31;
        xt[c][w] = x[xbase + (size_t)c * W_ + w];
    }
    #pragma unroll
    for (int k = 0; k < 32; ++k) {
        int idx = t + k * 256;
        int o = idx >> 7, c = idx & 127;
        WL[o][c] = Wq[idx] * LOG2E;     // fold log2e -> logits in log2 domain
    }
    __syncthreads();

    const int o  = t & 63;
    const int wg = t >> 6;

    float acc[8];
    const float bv = bq[o] * LOG2E;
    #pragma unroll
    for (int i = 0; i < 8; ++i) acc[i] = bv;

    #pragma unroll 4
    for (int c = 0; c < C_; ++c) {
        const float wv = WL[o][c];
        float xv[8];
        *(float4*)&xv[0] = *(const float4*)&xt[c][wg * 8 + 0];
        *(float4*)&xv[4] = *(const float4*)&xt[c][wg * 8 + 4];
        #pragma unroll
        for (int i = 0; i < 8; ++i) acc[i] = fmaf(wv, xv[i], acc[i]);
    }

    const size_t qbase = ((size_t)b * W_ + w0 + wg * 8) * CH_ + o;
    #pragma unroll
    for (int i = 0; i < 8; ++i)
        Qb[qbase + (size_t)i * CH_] = (bf16)acc[i];
}

__global__ __launch_bounds__(256) void kproj_kernel(
    const float* __restrict__ x,
    const float* __restrict__ Wk, const float* __restrict__ bk,
    bf16* __restrict__ Kfrag, bf16* __restrict__ Vfrag)
{
    __shared__ float xt[C_][36];
    __shared__ float WL[CH_][C_ + 1];

    const int t  = threadIdx.x;
    const int b  = blockIdx.x >> 7;
    const int w0 = (blockIdx.x & 127) << 5;    // 32 w = 2 jblks per block

    const size_t xbase = (size_t)b * C_ * W_ + w0;
    #pragma unroll
    for (int k = 0; k < 16; ++k) {
        int idx = t + k * 256;
        int c = idx >> 5, w = idx & 31;
        xt[c][w] = x[xbase + (size_t)c * W_ + w];
    }
    #pragma unroll
    for (int k = 0; k < 32; ++k) {
        int idx = t + k * 256;
        int o = idx >> 7, c = idx & 127;
        WL[o][c] = Wk[idx];
    }
    __syncthreads();

    const int o  = t & 63;
    const int wg = t >> 6;

    float acc[8];
    const float bv = bk[o];
    #pragma unroll
    for (int i = 0; i < 8; ++i) acc[i] = bv;

    #pragma unroll 4
    for (int c = 0; c < C_; ++c) {
        const float wv = WL[o][c];
        float xv[8];
        *(float4*)&xv[0] = *(const float4*)&xt[c][wg * 8 + 0];
        *(float4*)&xv[4] = *(const float4*)&xt[c][wg * 8 + 4];
        #pragma unroll
        for (int i = 0; i < 8; ++i) acc[i] = fmaf(wv, xv[i], acc[i]);
    }

    // K fragment stores (kh only): jblk stride 1024 elems
    const int jblk  = (w0 >> 4) + (wg >> 1);
    const int ibase = (wg & 1) * 8;
    const size_t kconst = (size_t)b * 262144 + (size_t)jblk * 1024
                        + (size_t)(o >> 5) * 512 + (size_t)((o >> 3) & 3) * 128
                        + (o & 7);
    #pragma unroll
    for (int i = 0; i < 8; ++i)
        Kfrag[kconst + (size_t)(ibase + i) * 8] = (bf16)acc[i];

    const int li = o & 15, gi = o >> 4;
    const int jb = wg >> 1;
    bf16* vfb = Vfrag + (size_t)b * 524288 + (size_t)((w0 >> 4) + jb) * 2048;
    #pragma unroll
    for (int tti = 0; tti < 4; ++tti) {
        const int tt = (wg & 1) * 4 + tti;
        const float4 xv4 = *(const float4*)&xt[tt * 16 + li][jb * 16 + 4 * gi];
        bf16x4 v4;
        v4[0] = (bf16)xv4.x; v4[1] = (bf16)xv4.y;
        v4[2] = (bf16)xv4.z; v4[3] = (bf16)xv4.w;
        *(bf16x4*)(vfb + tt * 256 + o * 4) = v4;
    }
}

// ---------------------------------------------------------------------------
// Attention macros (log2-domain softmax, single-bf16 QK^T)
// ---------------------------------------------------------------------------
#define LOADK(S, JB) { \
    const bf16* kp_ = KB + (size_t)(JB) * 1024; \
    kh0##S = *(const bf16x8*)(kp_); \
    kh1##S = *(const bf16x8*)(kp_ + 512); }

#define LOADV(S, JB) { \
    const bf16* vp_ = VB + (size_t)(JB) * 2048; \
    _Pragma("unroll") \
    for (int tt = 0; tt < 8; ++tt) \
        v##S[tt] = *(const bf16x4*)(vp_ + tt * 256); }

// defer-max: rescale only when tile max exceeds running max by 11.5 (=8*log2e);
// P bounded by 2^11.5 ~ 2896, safe in f32 l and bf16 P.
#define SOFTMAX(E, M, L, OACC, PS) { \
    const float mt = fmaxf(fmaxf(E[0], E[1]), fmaxf(E[2], E[3])); \
    if (__builtin_expect(__any(mt > M + 11.5f), 0)) { \
        float mr = mt; \
        mr = fmaxf(mr, __shfl_xor(mr, 16)); \
        mr = fmaxf(mr, __shfl_xor(mr, 32)); \
        const float mn = fmaxf(M, mr); \
        const float sc = exp2a(M - mn); \
        L *= sc; \
        _Pragma("unroll") \
        for (int t8 = 0; t8 < 8; ++t8) { \
            OACC[t8][0] *= sc; OACC[t8][1] *= sc; \
            OACC[t8][2] *= sc; OACC[t8][3] *= sc; } \
        M = mn; \
    } \
    const float p0 = exp2a(E[0] - M); \
    const float p1 = exp2a(E[1] - M); \
    const float p2 = exp2a(E[2] - M); \
    const float p3 = exp2a(E[3] - M); \
    L += (p0 + p1) + (p2 + p3); \
    bf16x4 pb; pb[0] = (bf16)p0; pb[1] = (bf16)p1; pb[2] = (bf16)p2; pb[3] = (bf16)p3; \
    PS = __builtin_bit_cast(short4v, pb); }

#define STEP2(S) { \
    f32x4 e0 = {0.f, 0.f, 0.f, 0.f}; \
    f32x4 e1 = {0.f, 0.f, 0.f, 0.f}; \
    e0 = mfma32bf(kh0##S, qb0_0, e0); \
    e0 = mfma32bf(kh1##S, qb1_0, e0); \
    e1 = mfma32bf(kh0##S, qb0_1, e1); \
    e1 = mfma32bf(kh1##S, qb1_1, e1); \
    short4v ps0, ps1; \
    SOFTMAX(e0, m0, l0, oacc0, ps0) \
    SOFTMAX(e1, m1, l1, oacc1, ps1) \
    _Pragma("unroll") \
    for (int t8 = 0; t8 < 8; ++t8) { \
        oacc0[t8] = mfma16bf(v##S[t8], ps0, oacc0[t8]); \
        oacc1[t8] = mfma16bf(v##S[t8], ps1, oacc1[t8]); } }

// ---------------------------------------------------------------------------
// Key-split flash attention partial: 32 queries/wave, 64 jblks/block (NS=4).
// ---------------------------------------------------------------------------
template<int NS>
__global__ __launch_bounds__(64, 2) void attn_partial_kernel(
    const bf16* __restrict__ Qb,
    const bf16* __restrict__ Kfrag, const bf16* __restrict__ Vfrag,
    bf16* __restrict__ Opart, float2* __restrict__ ml)
{
    constexpr int SJ = 256 / NS;
    const int lane = threadIdx.x;
    const int li = lane & 15;
    const int gi = lane >> 4;

    const int nwg = QBLKS * NS;
    const int bid = blockIdx.x;
    const int swz = (bid & 7) * (nwg / 8) + (bid >> 3);
    const int s   = swz >> 9;
    const int qi  = swz & (QBLKS - 1);
    const int b   = qi >> 7;
    const int i0  = (qi & 127) << 5;

    const size_t qoff = ((size_t)b * W_ + i0 + li) * CH_ + 8 * gi;
    const bf16x8 qb0_0 = *(const bf16x8*)(Qb + qoff);
    const bf16x8 qb1_0 = *(const bf16x8*)(Qb + qoff + 32);
    const bf16x8 qb0_1 = *(const bf16x8*)(Qb + qoff + 16 * CH_);
    const bf16x8 qb1_1 = *(const bf16x8*)(Qb + qoff + 16 * CH_ + 32);

    const bf16* KB = Kfrag + (size_t)b * 262144 + (size_t)lane * 8
                   + (size_t)s * SJ * 1024;
    const bf16* VB = Vfrag + (size_t)b * 524288 + (size_t)lane * 4
                   + (size_t)s * SJ * 2048;

    f32x4 oacc0[8], oacc1[8];
    #pragma unroll
    for (int t8 = 0; t8 < 8; ++t8) {
        oacc0[t8] = (f32x4){0.f, 0.f, 0.f, 0.f};
        oacc1[t8] = (f32x4){0.f, 0.f, 0.f, 0.f};
    }
    float m0 = -INFINITY, l0 = 0.f;
    float m1 = -INFINITY, l1 = 0.f;

    bf16x8 kh0A, kh1A, kh0B, kh1B;
    bf16x4 vA[8], vB[8];

    LOADK(A, 0) LOADV(A, 0)
    #pragma unroll 1
    for (int js = 0; js < SJ - 2; js += 2) {
        LOADK(B, js + 1) LOADV(B, js + 1)
        STEP2(A)
        LOADK(A, js + 2) LOADV(A, js + 2)
        STEP2(B)
    }
    LOADK(B, SJ - 1) LOADV(B, SJ - 1)
    STEP2(A)
    STEP2(B)

    l0 += __shfl_xor(l0, 16); l0 += __shfl_xor(l0, 32);
    l1 += __shfl_xor(l1, 16); l1 += __shfl_xor(l1, 32);

    const size_t pblk = (size_t)qi * NS + s;
    bf16* ob = Opart + pblk * 2 * 8 * 64 * 4;
    #pragma unroll
    for (int t8 = 0; t8 < 8; ++t8) {
        bf16x4 o0, o1;
        o0[0] = (bf16)oacc0[t8][0]; o0[1] = (bf16)oacc0[t8][1];
        o0[2] = (bf16)oacc0[t8][2]; o0[3] = (bf16)oacc0[t8][3];
        o1[0] = (bf16)oacc1[t8][0]; o1[1] = (bf16)oacc1[t8][1];
        o1[2] = (bf16)oacc1[t8][2]; o1[3] = (bf16)oacc1[t8][3];
        *(bf16x4*)(ob + ((size_t)t8 * 64 + lane) * 4)       = o0;
        *(bf16x4*)(ob + ((size_t)(8 + t8) * 64 + lane) * 4) = o1;
    }
    if (gi == 0) {
        ml[(pblk * 2 + 0) * 16 + li] = make_float2(m0, l0);
        ml[(pblk * 2 + 1) * 16 + li] = make_float2(m1, l1);
    }
}

// ---------------------------------------------------------------------------
// Merge (log2-domain m): out = sum_s 2^{m_s-M} O_s / sum_s 2^{m_s-M} l_s
// ---------------------------------------------------------------------------
template<int NS>
__global__ __launch_bounds__(256) void merge_kernel(
    const bf16* __restrict__ Opart, const float2* __restrict__ ml,
    float* __restrict__ out)
{
    const int t = threadIdx.x;
    const int lane = t & 63, grp = t >> 6;
    const int li = lane & 15, gi = lane >> 4;
    const int qi = blockIdx.x;
    const int b  = qi >> 7;
    const int i0 = (qi & 127) << 5;

    #pragma unroll
    for (int tile = 0; tile < 2; ++tile) {
        float ms[NS], ls[NS];
        float M = -INFINITY;
        #pragma unroll
        for (int s = 0; s < NS; ++s) {
            const float2 v = ml[(((size_t)qi * NS + s) * 2 + tile) * 16 + li];
            ms[s] = v.x; ls[s] = v.y;
            M = fmaxf(M, v.x);
        }
        float w[NS], den = 0.f;
        #pragma unroll
        for (int s = 0; s < NS; ++s) {
            w[s] = exp2a(ms[s] - M);
            den += w[s] * ls[s];
        }
        const float inv = 1.0f / den;

        #pragma unroll
        for (int t8g = 0; t8g < 2; ++t8g) {
            const int t8 = grp * 2 + t8g;
            float acc[4] = {0.f, 0.f, 0.f, 0.f};
            #pragma unroll
            for (int s = 0; s < NS; ++s) {
                const bf16x4 o4 = *(const bf16x4*)(Opart
                    + ((((size_t)qi * NS + s) * 2 + tile) * 8 + t8) * 256
                    + (size_t)lane * 4);
                acc[0] = fmaf(w[s], (float)o4[0], acc[0]);
                acc[1] = fmaf(w[s], (float)o4[1], acc[1]);
                acc[2] = fmaf(w[s], (float)o4[2], acc[2]);
                acc[3] = fmaf(w[s], (float)o4[3], acc[3]);
            }
            const int c0 = t8 * 16 + gi * 4;
            const int i  = i0 + tile * 16 + li;
            float* ob = out + ((size_t)b * C_ + c0) * W_ + i;
            ob[0 * (size_t)W_] = acc[0] * inv;
            ob[1 * (size_t)W_] = acc[1] * inv;
            ob[2 * (size_t)W_] = acc[2] * inv;
            ob[3 * (size_t)W_] = acc[3] * inv;
        }
    }
}

// ---------------------------------------------------------------------------
// Fallback tier: 16 queries/wave, all keys, direct output.
// ---------------------------------------------------------------------------
#define STEP1(S) { \
    f32x4 e = {0.f, 0.f, 0.f, 0.f}; \
    e = mfma32bf(kh0##S, qb0, e); \
    e = mfma32bf(kh1##S, qb1, e); \
    short4v ps; \
    SOFTMAX(e, m, l, oacc, ps) \
    _Pragma("unroll") \
    for (int t8 = 0; t8 < 8; ++t8) \
        oacc[t8] = mfma16bf(v##S[t8], ps, oacc[t8]); }

__global__ __launch_bounds__(64) void attn_kernel(
    const bf16* __restrict__ Qb,
    const bf16* __restrict__ Kfrag, const bf16* __restrict__ Vfrag,
    float* __restrict__ out)
{
    const int lane = threadIdx.x;
    const int li = lane & 15;
    const int gi = lane >> 4;

    const int nwg = B_ * (W_ / 16);
    const int bid = blockIdx.x;
    const int swz = (bid & 7) * (nwg / 8) + (bid >> 3);
    const int b   = swz >> 8;
    const int i0  = (swz & 255) << 4;

    const size_t qoff = ((size_t)b * W_ + i0 + li) * CH_ + 8 * gi;
    const bf16x8 qb0 = *(const bf16x8*)(Qb + qoff);
    const bf16x8 qb1 = *(const bf16x8*)(Qb + qoff + 32);

    const bf16* KB = Kfrag + (size_t)b * 262144 + (size_t)lane * 8;
    const bf16* VB = Vfrag + (size_t)b * 524288 + (size_t)lane * 4;

    f32x4 oacc[8];
    #pragma unroll
    for (int t8 = 0; t8 < 8; ++t8) oacc[t8] = (f32x4){0.f, 0.f, 0.f, 0.f};
    float m = -INFINITY;
    float l = 0.f;

    bf16x8 kh0A, kh1A, kh0B, kh1B;
    bf16x4 vA[8], vB[8];

    LOADK(A, 0) LOADV(A, 0)
    #pragma unroll 1
    for (int js = 0; js < 254; js += 2) {
        LOADK(B, js + 1) LOADV(B, js + 1)
        STEP1(A)
        LOADK(A, js + 2) LOADV(A, js + 2)
        STEP1(B)
    }
    LOADK(B, 255) LOADV(B, 255)
    STEP1(A)
    STEP1(B)

    l += __shfl_xor(l, 16);
    l += __shfl_xor(l, 32);
    const float inv = 1.0f / l;

    float* ob = out + (size_t)b * C_ * W_ + i0 + li;
    #pragma unroll
    for (int t8 = 0; t8 < 8; ++t8) {
        const int c0 = t8 * 16 + gi * 4;
        ob[(size_t)(c0 + 0) * W_] = oacc[t8][0] * inv;
        ob[(size_t)(c0 + 1) * W_] = oacc[t8][1] * inv;
        ob[(size_t)(c0 + 2) * W_] = oacc[t8][2] * inv;
        ob[(size_t)(c0 + 3) * W_] = oacc[t8][3] * inv;
    }
}

extern "C" void kernel_launch(void* const* d_in, const int* in_sizes, int n_in,
                              void* d_out, int out_size, void* d_ws, size_t ws_size,
                              hipStream_t stream)
{
    (void)in_sizes; (void)n_in; (void)out_size;

    const float* x  = (const float*)d_in[0];
    const float* Wq = (const float*)d_in[1];
    const float* bq = (const float*)d_in[2];
    const float* Wk = (const float*)d_in[3];
    const float* bk = (const float*)d_in[4];
    float* out = (float*)d_out;

    // ws: Qb 2MB | Kfrag 2MB | Vfrag 4MB | Opart 16MB @8MB | ml 0.5MB @24MB
    char* ws = (char*)d_ws;
    const size_t MB = 1024 * 1024;
    bf16* Qb    = (bf16*)(ws + 0 * MB);
    bf16* Kfrag = (bf16*)(ws + 2 * MB);
    bf16* Vfrag = (bf16*)(ws + 4 * MB);
    bf16* Opart = (bf16*)(ws + 8 * MB);
    float2* ml  = (float2*)(ws + 24 * MB);
    const size_t need = 24 * MB + (size_t)QBLKS * 4 * 2 * 16 * sizeof(float2);

    kproj_kernel<<<dim3(B_ * (W_ / 32)), dim3(256), 0, stream>>>(
        x, Wk, bk, Kfrag, Vfrag);
    qproj_kernel<<<dim3(B_ * (W_ / 32)), dim3(256), 0, stream>>>(
        x, Wq, bq, Qb);

    if (ws_size >= need) {
        attn_partial_kernel<4><<<dim3(QBLKS * 4), dim3(64), 0, stream>>>(
            Qb, Kfrag, Vfrag, Opart, ml);
        merge_kernel<4><<<dim3(QBLKS), dim3(256), 0, stream>>>(Opart, ml, out);
    } else {
        attn_kernel<<<dim3(B_ * (W_ / 16)), dim3(64), 0, stream>>>(
            Qb, Kfrag, Vfrag, out);
    }
}